// Round 6
// baseline (214.651 us; speedup 1.0000x reference)
//
#include <hip/hip_runtime.h>
#include <hip/hip_fp16.h>
#include <hip/hip_bf16.h>

#define D 128
#define NR 8        // ranges = XCDs
#define NCH_C 16    // chunks for counting  -> 128 blocks
#define NCH_S 32    // chunks for scatter   -> 256 blocks
#define RE_PAD 3200   // >= ceil(E/8)
#define RV_PAD 12544  // >= ceil(N/8)

typedef __attribute__((ext_vector_type(8))) short bf16x8;
typedef __attribute__((ext_vector_type(4))) float f32x4;

__device__ __forceinline__ __half2 u2h(unsigned u) { return __builtin_bit_cast(__half2, u); }

// ------- combined count: per-XCD-range histograms of both index arrays -----
__global__ __launch_bounds__(512) void count_comb(
    const int* __restrict__ edges, const int* __restrict__ vertex,
    int* __restrict__ C_E, int* __restrict__ C_V, int E, int N, int M) {
  __shared__ int he[RE_PAD];
  __shared__ int hv[RV_PAD];
  int r = blockIdx.x & (NR - 1), c = blockIdx.x >> 3;
  int RE = (E + NR - 1) / NR, RV = (N + NR - 1) / NR;
  int eLo = r * RE, eHi = min(eLo + RE, E);
  int vLo = r * RV, vHi = min(vLo + RV, N);
  int eLen = eHi - eLo, vLen = vHi - vLo;
  for (int i = threadIdx.x; i < eLen; i += 512) he[i] = 0;
  for (int i = threadIdx.x; i < vLen; i += 512) hv[i] = 0;
  __syncthreads();
  int n4 = M >> 2;
  int per = (n4 + NCH_C - 1) / NCH_C;
  int i0 = c * per, i1 = min(i0 + per, n4);
  for (int i = i0 + threadIdx.x; i < i1; i += 512) {
    int4 ek = ((const int4*)edges)[i];
    int4 vk = ((const int4*)vertex)[i];
    if (ek.x >= eLo && ek.x < eHi) atomicAdd(&he[ek.x - eLo], 1);
    if (ek.y >= eLo && ek.y < eHi) atomicAdd(&he[ek.y - eLo], 1);
    if (ek.z >= eLo && ek.z < eHi) atomicAdd(&he[ek.z - eLo], 1);
    if (ek.w >= eLo && ek.w < eHi) atomicAdd(&he[ek.w - eLo], 1);
    if (vk.x >= vLo && vk.x < vHi) atomicAdd(&hv[vk.x - vLo], 1);
    if (vk.y >= vLo && vk.y < vHi) atomicAdd(&hv[vk.y - vLo], 1);
    if (vk.z >= vLo && vk.z < vHi) atomicAdd(&hv[vk.z - vLo], 1);
    if (vk.w >= vLo && vk.w < vHi) atomicAdd(&hv[vk.w - vLo], 1);
  }
  if (c == NCH_C - 1) {
    for (int m = (n4 << 2) + threadIdx.x; m < M; m += 512) {
      int e = edges[m], v = vertex[m];
      if (e >= eLo && e < eHi) atomicAdd(&he[e - eLo], 1);
      if (v >= vLo && v < vHi) atomicAdd(&hv[v - vLo], 1);
    }
  }
  __syncthreads();
  for (int i = threadIdx.x; i < eLen; i += 512) { int t = he[i]; if (t) atomicAdd(&C_E[eLo + i], t); }
  for (int i = threadIdx.x; i < vLen; i += 512) { int t = hv[i]; if (t) atomicAdd(&C_V[vLo + i], t); }
}

// ---------------- hierarchical exclusive scan ------------------------------
__device__ __forceinline__ int block_exscan(int x, int tid, int* wsum) {
  int lane = tid & 63, w = tid >> 6;
  int v = x;
  #pragma unroll
  for (int off = 1; off < 64; off <<= 1) {
    int t = __shfl_up(v, off);
    if (lane >= off) v += t;
  }
  if (lane == 63) wsum[w] = v;
  __syncthreads();
  if (w == 0 && lane < 16) {
    int s = wsum[lane];
    #pragma unroll
    for (int off = 1; off < 16; off <<= 1) {
      int t = __shfl_up(s, off);
      if (lane >= off) s += t;
    }
    wsum[lane] = s;
  }
  __syncthreads();
  int woff = (w == 0) ? 0 : wsum[w - 1];
  return woff + v - x;
}

__global__ __launch_bounds__(1024) void scan_local(
    const int* __restrict__ C_E, int* __restrict__ A_E, int lenE,
    const int* __restrict__ C_V, int* __restrict__ A_V, int lenN,
    int* __restrict__ sums, int BE) {
  __shared__ int wsum[16];
  int b = blockIdx.x;
  const int* C = (b < BE) ? C_E : C_V;
  int* A = (b < BE) ? A_E : A_V;
  int len = (b < BE) ? lenE : lenN;
  int base = ((b < BE) ? b : (b - BE)) << 10;
  int i = base + threadIdx.x;
  int x = (i < len) ? C[i] : 0;
  int ex = block_exscan(x, threadIdx.x, wsum);
  if (i < len) A[i] = ex;
  if (threadIdx.x == 0) sums[b] = wsum[15];
}

__global__ __launch_bounds__(1024) void scan_sums(int* __restrict__ sums, int BE, int BV) {
  __shared__ int wsum[16];
  int off = (blockIdx.x == 0) ? 0 : BE;
  int len = (blockIdx.x == 0) ? BE : BV;
  int x = (threadIdx.x < len) ? sums[off + threadIdx.x] : 0;
  int ex = block_exscan(x, threadIdx.x, wsum);
  if (threadIdx.x < len) sums[off + threadIdx.x] = ex;
}

__global__ __launch_bounds__(1024) void scan_add(
    int* __restrict__ A_E, int* __restrict__ curE, int lenE,
    int* __restrict__ A_V, int* __restrict__ curV, int lenN,
    const int* __restrict__ sums, int BE) {
  int b = blockIdx.x;
  int* A = (b < BE) ? A_E : A_V;
  int* Cu = (b < BE) ? curE : curV;
  int len = (b < BE) ? lenE : lenN;
  int base = ((b < BE) ? b : (b - BE)) << 10;
  int i = base + threadIdx.x;
  if (i < len) {
    int v = A[i] + sums[b];
    A[i] = v;
    Cu[i] = v;
  }
}

// ------- combined scatter: XCD-local cursors and CSR regions ---------------
__global__ __launch_bounds__(512) void scatter_comb(
    const int* __restrict__ edges, const int* __restrict__ vertex,
    int* __restrict__ curE, int* __restrict__ curV,
    int* __restrict__ colE, int* __restrict__ colV, int E, int N, int M) {
  int r = blockIdx.x & (NR - 1), c = blockIdx.x >> 3;
  int RE = (E + NR - 1) / NR, RV = (N + NR - 1) / NR;
  int eLo = r * RE, eHi = min(eLo + RE, E);
  int vLo = r * RV, vHi = min(vLo + RV, N);
  int n4 = M >> 2;
  int per = (n4 + NCH_S - 1) / NCH_S;
  int i0 = c * per, i1 = min(i0 + per, n4);
  for (int i = i0 + threadIdx.x; i < i1; i += 512) {
    int4 ek = ((const int4*)edges)[i];
    int4 vk = ((const int4*)vertex)[i];
    int es[4] = {ek.x, ek.y, ek.z, ek.w};
    int vs[4] = {vk.x, vk.y, vk.z, vk.w};
    #pragma unroll
    for (int t = 0; t < 4; ++t) {
      if (es[t] >= eLo && es[t] < eHi) colE[atomicAdd(&curE[es[t]], 1)] = vs[t];
      if (vs[t] >= vLo && vs[t] < vHi) colV[atomicAdd(&curV[vs[t]], 1)] = es[t];
    }
  }
  if (c == NCH_S - 1) {
    for (int m = (n4 << 2) + threadIdx.x; m < M; m += 512) {
      int e = edges[m], v = vertex[m];
      if (e >= eLo && e < eHi) colE[atomicAdd(&curE[e], 1)] = v;
      if (v >= vLo && v < vHi) colV[atomicAdd(&curV[v], 1)] = e;
    }
  }
}

// ---------------- stage 1: vertex->edge mean, fp32 gather, 2 rows/instr ----
// wave per edge; lanes 0-31: even-position rows, lanes 32-63: odd-position
__global__ __launch_bounds__(256) void edge_agg_f(
    const float* __restrict__ X, const float* __restrict__ degE,
    const int* __restrict__ A_E, const int* __restrict__ C_E,
    const int* __restrict__ colE, uint2* __restrict__ Xe_h, int E) {
  int eid = blockIdx.x * 4 + (threadIdx.x >> 6);
  int lane = threadIdx.x & 63;
  if (eid >= E) return;
  int s = A_E[eid], cnt = C_E[eid], e = s + cnt;
  int half = lane >> 5, fl = lane & 31;
  const f32x4* X4 = (const f32x4*)X;  // row stride = 32 float4
  f32x4 acc = {0.f, 0.f, 0.f, 0.f};
  int idx = s;
  for (; idx + 8 <= e; idx += 8) {
    int ra = colE[idx + 0 + half];
    int rb = colE[idx + 2 + half];
    int rc = colE[idx + 4 + half];
    int rd = colE[idx + 6 + half];
    f32x4 ta = X4[(size_t)ra * 32 + fl];
    f32x4 tb = X4[(size_t)rb * 32 + fl];
    f32x4 tc = X4[(size_t)rc * 32 + fl];
    f32x4 td = X4[(size_t)rd * 32 + fl];
    acc += (ta + tb) + (tc + td);
  }
  for (; idx < e; idx += 2) {
    int p = idx + half;
    int r = colE[p < e ? p : idx];
    f32x4 t = X4[(size_t)r * 32 + fl];
    if (p < e) acc += t;
  }
  #pragma unroll
  for (int i = 0; i < 4; ++i) acc[i] += __shfl_xor(acc[i], 32);
  if (lane < 32) {
    float scale = degE[eid] / fmaxf((float)cnt, 1.0f);
    __half2 h0 = __float22half2_rn(make_float2(acc[0] * scale, acc[1] * scale));
    __half2 h1 = __float22half2_rn(make_float2(acc[2] * scale, acc[3] * scale));
    Xe_h[(size_t)eid * 32 + fl] =
        make_uint2(__builtin_bit_cast(unsigned, h0), __builtin_bit_cast(unsigned, h1));
  }
}

// ---------------- stage 2: edge->vertex sum (packed fp16) + LN + combine ---
// wave per vertex; uint2 = 4 fp16 features/lane; 2 rows per load instruction
__global__ __launch_bounds__(256) void vertex_ln_p(
    const uint2* __restrict__ Xe_h, const float* __restrict__ X0,
    const float* __restrict__ degV, const float* __restrict__ ln_w,
    const float* __restrict__ ln_b, const float* __restrict__ alpha_p,
    const int* __restrict__ A_V, const int* __restrict__ C_V,
    const int* __restrict__ colV, ushort* __restrict__ Xi_bf, int N) {
  int n = blockIdx.x * 4 + (threadIdx.x >> 6);
  int lane = threadIdx.x & 63;
  if (n >= N) return;
  int s = A_V[n], cnt = C_V[n], e = s + cnt;
  int half = lane >> 5, fl = lane & 31;
  __half2 accA = u2h(0u), accB = u2h(0u);
  int idx = s;
  for (; idx + 8 <= e; idx += 8) {
    int ra = colV[idx + 0 + half];
    int rb = colV[idx + 2 + half];
    int rc = colV[idx + 4 + half];
    int rd = colV[idx + 6 + half];
    uint2 va = Xe_h[(size_t)ra * 32 + fl];
    uint2 vb = Xe_h[(size_t)rb * 32 + fl];
    uint2 vc = Xe_h[(size_t)rc * 32 + fl];
    uint2 vd = Xe_h[(size_t)rd * 32 + fl];
    accA = __hadd2(accA, __hadd2(__hadd2(u2h(va.x), u2h(vb.x)), __hadd2(u2h(vc.x), u2h(vd.x))));
    accB = __hadd2(accB, __hadd2(__hadd2(u2h(va.y), u2h(vb.y)), __hadd2(u2h(vc.y), u2h(vd.y))));
  }
  for (; idx < e; idx += 2) {
    int p = idx + half;
    int r = colV[p < e ? p : idx];
    uint2 v = Xe_h[(size_t)r * 32 + fl];
    if (p < e) {
      accA = __hadd2(accA, u2h(v.x));
      accB = __hadd2(accB, u2h(v.y));
    }
  }
  float2 fA = __half22float2(accA), fB = __half22float2(accB);
  float t0 = fA.x, t1 = fA.y, t2 = fB.x, t3 = fB.y;
  t0 += __shfl_xor(t0, 32);
  t1 += __shfl_xor(t1, 32);
  t2 += __shfl_xor(t2, 32);
  t3 += __shfl_xor(t3, 32);
  float sm = (t0 + t1) + (t2 + t3);
  float q = t0 * t0 + t1 * t1 + t2 * t2 + t3 * t3;
  #pragma unroll
  for (int off = 1; off < 32; off <<= 1) {
    sm += __shfl_xor(sm, off);
    q += __shfl_xor(q, off);
  }
  if (lane < 32) {
    float dv = degV[n];
    float csc = 2.f * dv;
    float mu = csc * sm * (1.f / 128.f);
    float var = csc * csc * q * (1.f / 128.f) - mu * mu;
    float rstd = rsqrtf(var + 1e-5f);
    f32x4 lw = ((const f32x4*)ln_w)[fl];
    f32x4 lb = ((const f32x4*)ln_b)[fl];
    f32x4 x0 = ((const f32x4*)X0)[(size_t)n * 32 + fl];
    float alpha = *alpha_p;
    float tt[4] = {t0, t1, t2, t3};
    unsigned u0 = 0, u1 = 0;
    ushort ob[4];
    #pragma unroll
    for (int i = 0; i < 4; ++i) {
      float xh = csc * tt[i];
      float xn = (xh - mu) * rstd * lw[i] + lb[i];
      float xi = (1.f - alpha) * xn + alpha * x0[i];
      __hip_bfloat16 b = __float2bfloat16(xi);
      ob[i] = __builtin_bit_cast(ushort, b);
    }
    u0 = (unsigned)ob[0] | ((unsigned)ob[1] << 16);
    u1 = (unsigned)ob[2] | ((unsigned)ob[3] << 16);
    ((uint2*)Xi_bf)[(size_t)n * 32 + fl] = make_uint2(u0, u1);
  }
}

// ---------------- Weff = beta*W^T + (1-beta)*I, bf16, stored [j][k] -------
__global__ void wprep_kernel(const float* __restrict__ W, const float* __restrict__ beta_p,
                             ushort* __restrict__ Wbf) {
  int idx = blockIdx.x * 256 + threadIdx.x;
  int j = idx >> 7, k = idx & 127;
  float beta = *beta_p;
  float v = beta * W[idx] + ((j == k) ? (1.f - beta) : 0.f);
  __hip_bfloat16 b = __float2bfloat16(v);
  Wbf[idx] = *(ushort*)&b;
}

// ---------------- stage 3: out = Xi @ Weff via MFMA bf16 ------------------
__global__ __launch_bounds__(256) void gemm_out(
    const ushort* __restrict__ Xi_bf, const ushort* __restrict__ Wbf,
    float* __restrict__ out, int N) {
  __shared__ __align__(16) ushort Wl[128 * 128];
  for (int t = threadIdx.x; t < 2048; t += 256) {
    int j = t >> 4, chunk = t & 15;
    bf16x8 v = ((const bf16x8*)Wbf)[t];
    ((bf16x8*)Wl)[j * 16 + (chunk ^ (j & 7))] = v;
  }
  __syncthreads();
  int wv = threadIdx.x >> 6, lane = threadIdx.x & 63;
  int row0 = blockIdx.x * 128 + wv * 32;
  f32x4 acc[2][8] = {};
  #pragma unroll
  for (int ks = 0; ks < 4; ++ks) {
    bf16x8 a[2];
    #pragma unroll
    for (int rt = 0; rt < 2; ++rt) {
      int row = row0 + rt * 16 + (lane & 15);
      row = row < N ? row : N - 1;
      a[rt] = *(const bf16x8*)(Xi_bf + (size_t)row * 128 + ks * 32 + (lane >> 4) * 8);
    }
    int chunk = ks * 4 + (lane >> 4);
    #pragma unroll
    for (int c = 0; c < 8; ++c) {
      int col = c * 16 + (lane & 15);
      bf16x8 bb = ((const bf16x8*)Wl)[col * 16 + (chunk ^ (col & 7))];
      acc[0][c] = __builtin_amdgcn_mfma_f32_16x16x32_bf16(a[0], bb, acc[0][c], 0, 0, 0);
      acc[1][c] = __builtin_amdgcn_mfma_f32_16x16x32_bf16(a[1], bb, acc[1][c], 0, 0, 0);
    }
  }
  #pragma unroll
  for (int rt = 0; rt < 2; ++rt) {
    #pragma unroll
    for (int c = 0; c < 8; ++c) {
      #pragma unroll
      for (int i = 0; i < 4; ++i) {
        int row = row0 + rt * 16 + (lane >> 4) * 4 + i;
        int col = c * 16 + (lane & 15);
        if (row < N) out[(size_t)row * 128 + col] = acc[rt][c][i];
      }
    }
  }
}

extern "C" void kernel_launch(void* const* d_in, const int* in_sizes, int n_in,
                              void* d_out, int out_size, void* d_ws, size_t ws_size,
                              hipStream_t stream) {
  const float* X     = (const float*)d_in[0];
  const float* X0    = (const float*)d_in[1];
  const float* degE  = (const float*)d_in[2];
  const float* degV  = (const float*)d_in[3];
  const float* W     = (const float*)d_in[4];
  const float* alpha = (const float*)d_in[5];
  const float* beta  = (const float*)d_in[6];
  const float* lnw   = (const float*)d_in[7];
  const float* lnb   = (const float*)d_in[8];
  const int* vertex  = (const int*)d_in[9];
  const int* edges   = (const int*)d_in[10];

  const int N = in_sizes[0] / D;
  const int E = in_sizes[2];
  const int M = in_sizes[9];

  const int BE = (E + 1023) >> 10;
  const int BV = (N + 1023) >> 10;

  char* p = (char*)d_ws;
  auto alloc = [&](size_t bytes) { char* r = p; p += (bytes + 255) & ~255ull; return r; };
  int* A_E  = (int*)alloc((size_t)E * 4);
  int* A_V  = (int*)alloc((size_t)N * 4);
  int* C_E  = (int*)alloc((size_t)E * 4);
  int* C_V  = (int*)alloc((size_t)N * 4);
  int* curE = (int*)alloc((size_t)E * 4);
  int* curV = (int*)alloc((size_t)N * 4);
  int* sums = (int*)alloc(1024);
  int* colE = (int*)alloc((size_t)M * 4);
  int* colV = (int*)alloc((size_t)M * 4);
  uint2* Xe_h = (uint2*)alloc((size_t)E * D * 2);      // E x 128 fp16
  ushort* Xi_bf = (ushort*)alloc((size_t)N * D * 2);   // N x 128 bf16
  ushort* Wbf   = (ushort*)alloc(16384 * 2);

  hipMemsetAsync(C_E, 0, (size_t)E * 4, stream);
  hipMemsetAsync(C_V, 0, (size_t)N * 4, stream);
  count_comb<<<NR * NCH_C, 512, 0, stream>>>(edges, vertex, C_E, C_V, E, N, M);
  scan_local<<<BE + BV, 1024, 0, stream>>>(C_E, A_E, E, C_V, A_V, N, sums, BE);
  scan_sums<<<2, 1024, 0, stream>>>(sums, BE, BV);
  scan_add<<<BE + BV, 1024, 0, stream>>>(A_E, curE, E, A_V, curV, N, sums, BE);
  scatter_comb<<<NR * NCH_S, 512, 0, stream>>>(edges, vertex, curE, curV, colE, colV, E, N, M);
  edge_agg_f<<<(E + 3) / 4, 256, 0, stream>>>(X, degE, A_E, C_E, colE, Xe_h, E);
  vertex_ln_p<<<(N + 3) / 4, 256, 0, stream>>>(Xe_h, X0, degV, lnw, lnb, alpha,
                                               A_V, C_V, colV, Xi_bf, N);
  wprep_kernel<<<64, 256, 0, stream>>>(W, beta, Wbf);
  gemm_out<<<(N + 127) / 128, 256, 0, stream>>>(Xi_bf, Wbf, (float*)d_out, N);
}

// Round 7
// 188.184 us; speedup vs baseline: 1.1406x; 1.1406x over previous
//
#include <hip/hip_runtime.h>
#include <hip/hip_fp16.h>
#include <hip/hip_bf16.h>

#define D 128
#define NR 8        // ranges = XCDs
#define NCH_C 16    // chunks for counting  -> 128 count blocks
#define NCH_S 32    // chunks for scatter   -> 256 blocks
#define CVT_BLOCKS 512
#define RE_PAD 3200   // >= ceil(E/8)
#define RV_PAD 12544  // >= ceil(N/8)

typedef __attribute__((ext_vector_type(8))) short bf16x8;
typedef __attribute__((ext_vector_type(4))) float f32x4;

__device__ __forceinline__ __half2 u2h(unsigned u) { return __builtin_bit_cast(__half2, u); }

// ------- fused: per-XCD-range histograms + fp32->fp16 conversion -----------
__global__ __launch_bounds__(512) void count_and_half(
    const int* __restrict__ edges, const int* __restrict__ vertex,
    int* __restrict__ C_E, int* __restrict__ C_V, int E, int N, int M,
    const float* __restrict__ X, uint2* __restrict__ Xh, int n4) {
  __shared__ int he[RE_PAD];
  __shared__ int hv[RV_PAD];
  int b = blockIdx.x;
  if (b >= NR * NCH_C) {
    // conversion blocks: stream X (fp32) -> Xh (fp16), float4 granularity
    const f32x4* X4 = (const f32x4*)X;
    int stride = (gridDim.x - NR * NCH_C) * 512;
    for (int i = (b - NR * NCH_C) * 512 + threadIdx.x; i < n4; i += stride) {
      f32x4 v = X4[i];
      __half2 h0 = __float22half2_rn(make_float2(v[0], v[1]));
      __half2 h1 = __float22half2_rn(make_float2(v[2], v[3]));
      Xh[i] = make_uint2(__builtin_bit_cast(unsigned, h0), __builtin_bit_cast(unsigned, h1));
    }
    return;
  }
  int r = b & (NR - 1), c = b >> 3;
  int RE = (E + NR - 1) / NR, RV = (N + NR - 1) / NR;
  int eLo = r * RE, eHi = min(eLo + RE, E);
  int vLo = r * RV, vHi = min(vLo + RV, N);
  int eLen = eHi - eLo, vLen = vHi - vLo;
  for (int i = threadIdx.x; i < eLen; i += 512) he[i] = 0;
  for (int i = threadIdx.x; i < vLen; i += 512) hv[i] = 0;
  __syncthreads();
  int m4 = M >> 2;
  int per = (m4 + NCH_C - 1) / NCH_C;
  int i0 = c * per, i1 = min(i0 + per, m4);
  for (int i = i0 + threadIdx.x; i < i1; i += 512) {
    int4 ek = ((const int4*)edges)[i];
    int4 vk = ((const int4*)vertex)[i];
    if (ek.x >= eLo && ek.x < eHi) atomicAdd(&he[ek.x - eLo], 1);
    if (ek.y >= eLo && ek.y < eHi) atomicAdd(&he[ek.y - eLo], 1);
    if (ek.z >= eLo && ek.z < eHi) atomicAdd(&he[ek.z - eLo], 1);
    if (ek.w >= eLo && ek.w < eHi) atomicAdd(&he[ek.w - eLo], 1);
    if (vk.x >= vLo && vk.x < vHi) atomicAdd(&hv[vk.x - vLo], 1);
    if (vk.y >= vLo && vk.y < vHi) atomicAdd(&hv[vk.y - vLo], 1);
    if (vk.z >= vLo && vk.z < vHi) atomicAdd(&hv[vk.z - vLo], 1);
    if (vk.w >= vLo && vk.w < vHi) atomicAdd(&hv[vk.w - vLo], 1);
  }
  if (c == NCH_C - 1) {
    for (int m = (m4 << 2) + threadIdx.x; m < M; m += 512) {
      int e = edges[m], v = vertex[m];
      if (e >= eLo && e < eHi) atomicAdd(&he[e - eLo], 1);
      if (v >= vLo && v < vHi) atomicAdd(&hv[v - vLo], 1);
    }
  }
  __syncthreads();
  for (int i = threadIdx.x; i < eLen; i += 512) { int t = he[i]; if (t) atomicAdd(&C_E[eLo + i], t); }
  for (int i = threadIdx.x; i < vLen; i += 512) { int t = hv[i]; if (t) atomicAdd(&C_V[vLo + i], t); }
}

// ---------------- hierarchical exclusive scan ------------------------------
__device__ __forceinline__ int block_exscan(int x, int tid, int* wsum) {
  int lane = tid & 63, w = tid >> 6;
  int v = x;
  #pragma unroll
  for (int off = 1; off < 64; off <<= 1) {
    int t = __shfl_up(v, off);
    if (lane >= off) v += t;
  }
  if (lane == 63) wsum[w] = v;
  __syncthreads();
  if (w == 0 && lane < 16) {
    int s = wsum[lane];
    #pragma unroll
    for (int off = 1; off < 16; off <<= 1) {
      int t = __shfl_up(s, off);
      if (lane >= off) s += t;
    }
    wsum[lane] = s;
  }
  __syncthreads();
  int woff = (w == 0) ? 0 : wsum[w - 1];
  return woff + v - x;
}

__global__ __launch_bounds__(1024) void scan_local(
    const int* __restrict__ C_E, int* __restrict__ A_E, int lenE,
    const int* __restrict__ C_V, int* __restrict__ A_V, int lenN,
    int* __restrict__ sums, int BE) {
  __shared__ int wsum[16];
  int b = blockIdx.x;
  const int* C = (b < BE) ? C_E : C_V;
  int* A = (b < BE) ? A_E : A_V;
  int len = (b < BE) ? lenE : lenN;
  int base = ((b < BE) ? b : (b - BE)) << 10;
  int i = base + threadIdx.x;
  int x = (i < len) ? C[i] : 0;
  int ex = block_exscan(x, threadIdx.x, wsum);
  if (i < len) A[i] = ex;
  if (threadIdx.x == 0) sums[b] = wsum[15];
}

__global__ __launch_bounds__(1024) void scan_sums(int* __restrict__ sums, int BE, int BV) {
  __shared__ int wsum[16];
  int off = (blockIdx.x == 0) ? 0 : BE;
  int len = (blockIdx.x == 0) ? BE : BV;
  int x = (threadIdx.x < len) ? sums[off + threadIdx.x] : 0;
  int ex = block_exscan(x, threadIdx.x, wsum);
  if (threadIdx.x < len) sums[off + threadIdx.x] = ex;
}

__global__ __launch_bounds__(1024) void scan_add(
    int* __restrict__ A_E, int* __restrict__ curE, int lenE,
    int* __restrict__ A_V, int* __restrict__ curV, int lenN,
    const int* __restrict__ sums, int BE) {
  int b = blockIdx.x;
  int* A = (b < BE) ? A_E : A_V;
  int* Cu = (b < BE) ? curE : curV;
  int len = (b < BE) ? lenE : lenN;
  int base = ((b < BE) ? b : (b - BE)) << 10;
  int i = base + threadIdx.x;
  if (i < len) {
    int v = A[i] + sums[b];
    A[i] = v;
    Cu[i] = v;
  }
}

// ------- combined scatter: XCD-local cursors and CSR regions ---------------
__global__ __launch_bounds__(512) void scatter_comb(
    const int* __restrict__ edges, const int* __restrict__ vertex,
    int* __restrict__ curE, int* __restrict__ curV,
    int* __restrict__ colE, int* __restrict__ colV, int E, int N, int M) {
  int r = blockIdx.x & (NR - 1), c = blockIdx.x >> 3;
  int RE = (E + NR - 1) / NR, RV = (N + NR - 1) / NR;
  int eLo = r * RE, eHi = min(eLo + RE, E);
  int vLo = r * RV, vHi = min(vLo + RV, N);
  int n4 = M >> 2;
  int per = (n4 + NCH_S - 1) / NCH_S;
  int i0 = c * per, i1 = min(i0 + per, n4);
  for (int i = i0 + threadIdx.x; i < i1; i += 512) {
    int4 ek = ((const int4*)edges)[i];
    int4 vk = ((const int4*)vertex)[i];
    int es[4] = {ek.x, ek.y, ek.z, ek.w};
    int vs[4] = {vk.x, vk.y, vk.z, vk.w};
    #pragma unroll
    for (int t = 0; t < 4; ++t) {
      if (es[t] >= eLo && es[t] < eHi) colE[atomicAdd(&curE[es[t]], 1)] = vs[t];
      if (vs[t] >= vLo && vs[t] < vHi) colV[atomicAdd(&curV[vs[t]], 1)] = es[t];
    }
  }
  if (c == NCH_S - 1) {
    for (int m = (n4 << 2) + threadIdx.x; m < M; m += 512) {
      int e = edges[m], v = vertex[m];
      if (e >= eLo && e < eHi) colE[atomicAdd(&curE[e], 1)] = v;
      if (v >= vLo && v < vHi) colV[atomicAdd(&curV[v], 1)] = e;
    }
  }
}

// ---------------- stage 1: vertex->edge mean (fp16, parity, batch tail) ----
// wave per edge; lane = (parity of incidence, 32 feature-lanes); uint2 = 4 fp16
__global__ __launch_bounds__(256) void edge_agg_h2(
    const uint2* __restrict__ Xh, const float* __restrict__ degE,
    const int* __restrict__ A_E, const int* __restrict__ C_E,
    const int* __restrict__ colE, uint2* __restrict__ Xe_h, int E) {
  int eid = blockIdx.x * 4 + (threadIdx.x >> 6);
  int lane = threadIdx.x & 63;
  if (eid >= E) return;
  int s = A_E[eid], cnt = C_E[eid], e = s + cnt;
  int half = lane >> 5, fl = lane & 31;
  __half2 accA = u2h(0u), accB = u2h(0u);
  int idx = s;
  for (; idx + 8 <= e; idx += 8) {
    int ra = colE[idx + 0 + half];
    int rb = colE[idx + 2 + half];
    int rc = colE[idx + 4 + half];
    int rd = colE[idx + 6 + half];
    uint2 va = Xh[(size_t)ra * 32 + fl];
    uint2 vb = Xh[(size_t)rb * 32 + fl];
    uint2 vc = Xh[(size_t)rc * 32 + fl];
    uint2 vd = Xh[(size_t)rd * 32 + fl];
    accA = __hadd2(accA, __hadd2(__hadd2(u2h(va.x), u2h(vb.x)), __hadd2(u2h(vc.x), u2h(vd.x))));
    accB = __hadd2(accB, __hadd2(__hadd2(u2h(va.y), u2h(vb.y)), __hadd2(u2h(vc.y), u2h(vd.y))));
  }
  int rem = e - idx;  // 0..7: one predicated batch (4 loads in flight per lane)
  if (rem > 0) {
    int r[4];
    #pragma unroll
    for (int t = 0; t < 4; ++t) {
      int p = 2 * t + half;
      r[t] = colE[idx + (p < rem ? p : 0)];
    }
    #pragma unroll
    for (int t = 0; t < 4; ++t) {
      uint2 v = Xh[(size_t)r[t] * 32 + fl];
      if (2 * t + half < rem) {
        accA = __hadd2(accA, u2h(v.x));
        accB = __hadd2(accB, u2h(v.y));
      }
    }
  }
  // combine parity halves
  float2 fA = __half22float2(accA), fB = __half22float2(accB);
  float t0 = fA.x, t1 = fA.y, t2 = fB.x, t3 = fB.y;
  t0 += __shfl_xor(t0, 32);
  t1 += __shfl_xor(t1, 32);
  t2 += __shfl_xor(t2, 32);
  t3 += __shfl_xor(t3, 32);
  if (lane < 32) {
    float scale = degE[eid] / fmaxf((float)cnt, 1.0f);
    __half2 h0 = __float22half2_rn(make_float2(t0 * scale, t1 * scale));
    __half2 h1 = __float22half2_rn(make_float2(t2 * scale, t3 * scale));
    Xe_h[(size_t)eid * 32 + fl] =
        make_uint2(__builtin_bit_cast(unsigned, h0), __builtin_bit_cast(unsigned, h1));
  }
}

// ---------------- stage 2: edge->vertex sum + LN + combine -----------------
// HALF-wave (32 lanes) per vertex; predicated 8-deep gather batches (high MLP)
__global__ __launch_bounds__(256) void vertex_ln_h(
    const uint2* __restrict__ Xe_h, const float* __restrict__ X0,
    const float* __restrict__ degV, const float* __restrict__ ln_w,
    const float* __restrict__ ln_b, const float* __restrict__ alpha_p,
    const int* __restrict__ A_V, const int* __restrict__ C_V,
    const int* __restrict__ colV, ushort* __restrict__ Xi_bf, int N) {
  int fl = threadIdx.x & 31;
  int n = blockIdx.x * 8 + (threadIdx.x >> 5);  // 8 half-waves per block
  if (n >= N) return;
  int s = A_V[n], cnt = C_V[n];
  __half2 accA = u2h(0u), accB = u2h(0u);
  int idx = s, rem = cnt;
  while (rem > 0) {
    int r[8];
    #pragma unroll
    for (int t = 0; t < 8; ++t) r[t] = colV[idx + (t < rem ? t : 0)];
    #pragma unroll
    for (int t = 0; t < 8; ++t) {
      uint2 v = Xe_h[(size_t)r[t] * 32 + fl];
      if (t < rem) {
        accA = __hadd2(accA, u2h(v.x));
        accB = __hadd2(accB, u2h(v.y));
      }
    }
    idx += 8;
    rem -= 8;
  }
  float2 fA = __half22float2(accA), fB = __half22float2(accB);
  float t0 = fA.x, t1 = fA.y, t2 = fB.x, t3 = fB.y;
  float sm = (t0 + t1) + (t2 + t3);
  float q = t0 * t0 + t1 * t1 + t2 * t2 + t3 * t3;
  #pragma unroll
  for (int off = 1; off < 32; off <<= 1) {  // reduce within the 32-lane half
    sm += __shfl_xor(sm, off);
    q += __shfl_xor(q, off);
  }
  float dv = degV[n];
  float csc = 2.f * dv;
  float mu = csc * sm * (1.f / 128.f);
  float var = csc * csc * q * (1.f / 128.f) - mu * mu;
  float rstd = rsqrtf(var + 1e-5f);
  f32x4 lw = ((const f32x4*)ln_w)[fl];
  f32x4 lb = ((const f32x4*)ln_b)[fl];
  f32x4 x0 = ((const f32x4*)X0)[(size_t)n * 32 + fl];
  float alpha = *alpha_p;
  float tt[4] = {t0, t1, t2, t3};
  ushort ob[4];
  #pragma unroll
  for (int i = 0; i < 4; ++i) {
    float xh = csc * tt[i];
    float xn = (xh - mu) * rstd * lw[i] + lb[i];
    float xi = (1.f - alpha) * xn + alpha * x0[i];
    __hip_bfloat16 bb = __float2bfloat16(xi);
    ob[i] = __builtin_bit_cast(ushort, bb);
  }
  unsigned u0 = (unsigned)ob[0] | ((unsigned)ob[1] << 16);
  unsigned u1 = (unsigned)ob[2] | ((unsigned)ob[3] << 16);
  ((uint2*)Xi_bf)[(size_t)n * 32 + fl] = make_uint2(u0, u1);
}

// ---------------- Weff = beta*W^T + (1-beta)*I, bf16, stored [j][k] -------
__global__ void wprep_kernel(const float* __restrict__ W, const float* __restrict__ beta_p,
                             ushort* __restrict__ Wbf) {
  int idx = blockIdx.x * 256 + threadIdx.x;
  int j = idx >> 7, k = idx & 127;
  float beta = *beta_p;
  float v = beta * W[idx] + ((j == k) ? (1.f - beta) : 0.f);
  __hip_bfloat16 b = __float2bfloat16(v);
  Wbf[idx] = *(ushort*)&b;
}

// ---------------- stage 3: out = Xi @ Weff via MFMA bf16 ------------------
__global__ __launch_bounds__(256) void gemm_out(
    const ushort* __restrict__ Xi_bf, const ushort* __restrict__ Wbf,
    float* __restrict__ out, int N) {
  __shared__ __align__(16) ushort Wl[128 * 128];
  for (int t = threadIdx.x; t < 2048; t += 256) {
    int j = t >> 4, chunk = t & 15;
    bf16x8 v = ((const bf16x8*)Wbf)[t];
    ((bf16x8*)Wl)[j * 16 + (chunk ^ (j & 7))] = v;
  }
  __syncthreads();
  int wv = threadIdx.x >> 6, lane = threadIdx.x & 63;
  int row0 = blockIdx.x * 128 + wv * 32;
  f32x4 acc[2][8] = {};
  #pragma unroll
  for (int ks = 0; ks < 4; ++ks) {
    bf16x8 a[2];
    #pragma unroll
    for (int rt = 0; rt < 2; ++rt) {
      int row = row0 + rt * 16 + (lane & 15);
      row = row < N ? row : N - 1;
      a[rt] = *(const bf16x8*)(Xi_bf + (size_t)row * 128 + ks * 32 + (lane >> 4) * 8);
    }
    int chunk = ks * 4 + (lane >> 4);
    #pragma unroll
    for (int c = 0; c < 8; ++c) {
      int col = c * 16 + (lane & 15);
      bf16x8 bb = ((const bf16x8*)Wl)[col * 16 + (chunk ^ (col & 7))];
      acc[0][c] = __builtin_amdgcn_mfma_f32_16x16x32_bf16(a[0], bb, acc[0][c], 0, 0, 0);
      acc[1][c] = __builtin_amdgcn_mfma_f32_16x16x32_bf16(a[1], bb, acc[1][c], 0, 0, 0);
    }
  }
  #pragma unroll
  for (int rt = 0; rt < 2; ++rt) {
    #pragma unroll
    for (int c = 0; c < 8; ++c) {
      #pragma unroll
      for (int i = 0; i < 4; ++i) {
        int row = row0 + rt * 16 + (lane >> 4) * 4 + i;
        int col = c * 16 + (lane & 15);
        if (row < N) out[(size_t)row * 128 + col] = acc[rt][c][i];
      }
    }
  }
}

extern "C" void kernel_launch(void* const* d_in, const int* in_sizes, int n_in,
                              void* d_out, int out_size, void* d_ws, size_t ws_size,
                              hipStream_t stream) {
  const float* X     = (const float*)d_in[0];
  const float* X0    = (const float*)d_in[1];
  const float* degE  = (const float*)d_in[2];
  const float* degV  = (const float*)d_in[3];
  const float* W     = (const float*)d_in[4];
  const float* alpha = (const float*)d_in[5];
  const float* beta  = (const float*)d_in[6];
  const float* lnw   = (const float*)d_in[7];
  const float* lnb   = (const float*)d_in[8];
  const int* vertex  = (const int*)d_in[9];
  const int* edges   = (const int*)d_in[10];

  const int N = in_sizes[0] / D;
  const int E = in_sizes[2];
  const int M = in_sizes[9];

  const int BE = (E + 1023) >> 10;
  const int BV = (N + 1023) >> 10;

  char* p = (char*)d_ws;
  auto alloc = [&](size_t bytes) { char* r = p; p += (bytes + 255) & ~255ull; return r; };
  int* A_E  = (int*)alloc((size_t)E * 4);
  int* A_V  = (int*)alloc((size_t)N * 4);
  int* C_E  = (int*)alloc((size_t)E * 4);
  int* C_V  = (int*)alloc((size_t)N * 4);
  int* curE = (int*)alloc((size_t)E * 4);
  int* curV = (int*)alloc((size_t)N * 4);
  int* sums = (int*)alloc(1024);
  int* colE = (int*)alloc((size_t)M * 4);
  int* colV = (int*)alloc((size_t)M * 4);
  uint2* X_h  = (uint2*)alloc((size_t)N * D * 2);      // N x 128 fp16
  uint2* Xe_h = (uint2*)alloc((size_t)E * D * 2);      // E x 128 fp16
  ushort* Xi_bf = (ushort*)alloc((size_t)N * D * 2);   // N x 128 bf16
  ushort* Wbf   = (ushort*)alloc(16384 * 2);

  hipMemsetAsync(C_E, 0, (size_t)E * 4, stream);
  hipMemsetAsync(C_V, 0, (size_t)N * 4, stream);
  count_and_half<<<NR * NCH_C + CVT_BLOCKS, 512, 0, stream>>>(
      edges, vertex, C_E, C_V, E, N, M, X, X_h, N * D / 4);
  scan_local<<<BE + BV, 1024, 0, stream>>>(C_E, A_E, E, C_V, A_V, N, sums, BE);
  scan_sums<<<2, 1024, 0, stream>>>(sums, BE, BV);
  scan_add<<<BE + BV, 1024, 0, stream>>>(A_E, curE, E, A_V, curV, N, sums, BE);
  scatter_comb<<<NR * NCH_S, 512, 0, stream>>>(edges, vertex, curE, curV, colE, colV, E, N, M);
  edge_agg_h2<<<(E + 3) / 4, 256, 0, stream>>>(X_h, degE, A_E, C_E, colE, Xe_h, E);
  vertex_ln_h<<<(N + 7) / 8, 256, 0, stream>>>(Xe_h, X0, degV, lnw, lnb, alpha,
                                               A_V, C_V, colV, Xi_bf, N);
  wprep_kernel<<<64, 256, 0, stream>>>(W, beta, Wbf);
  gemm_out<<<(N + 127) / 128, 256, 0, stream>>>(Xi_bf, Wbf, (float*)d_out, N);
}

// Round 8
// 143.479 us; speedup vs baseline: 1.4960x; 1.3116x over previous
//
#include <hip/hip_runtime.h>
#include <hip/hip_fp16.h>
#include <hip/hip_bf16.h>

#define D 128
#define NRR 16      // ranges (2 per XCD; range r -> XCD r%8 under blockIdx%8 round-robin)
#define NCH 32      // chunks per range
#define CVT_BLOCKS 512
#define RE_SL 1600   // >= ceil(E/16) = 1563
#define RV_SL 6272   // >= ceil(N/16) = 6250

typedef __attribute__((ext_vector_type(8))) short bf16x8;
typedef __attribute__((ext_vector_type(4))) float f32x4;

__device__ __forceinline__ __half2 u2h(unsigned u) { return __builtin_bit_cast(__half2, u); }

// ------- count: per-(range,chunk) LDS histograms -> dense tables; + cvt ----
__global__ __launch_bounds__(512) void count_tab(
    const int* __restrict__ edges, const int* __restrict__ vertex,
    int* __restrict__ T_E, int* __restrict__ T_V, int E, int N, int M,
    const float* __restrict__ X, uint2* __restrict__ Xh, int xn4) {
  __shared__ int he[RE_SL];
  __shared__ int hv[RV_SL];
  int b = blockIdx.x;
  if (b >= NRR * NCH) {
    // conversion blocks: stream X (fp32) -> Xh (fp16)
    const f32x4* X4 = (const f32x4*)X;
    int stride = (gridDim.x - NRR * NCH) * 512;
    for (int i = (b - NRR * NCH) * 512 + threadIdx.x; i < xn4; i += stride) {
      f32x4 v = X4[i];
      __half2 h0 = __float22half2_rn(make_float2(v[0], v[1]));
      __half2 h1 = __float22half2_rn(make_float2(v[2], v[3]));
      Xh[i] = make_uint2(__builtin_bit_cast(unsigned, h0), __builtin_bit_cast(unsigned, h1));
    }
    return;
  }
  int r = b & (NRR - 1), c = b >> 4;
  int RE = (E + NRR - 1) / NRR, RV = (N + NRR - 1) / NRR;
  int eLo = r * RE, eHi = min(eLo + RE, E);
  int vLo = r * RV, vHi = min(vLo + RV, N);
  int eLen = eHi - eLo, vLen = vHi - vLo;
  for (int i = threadIdx.x; i < eLen; i += 512) he[i] = 0;
  for (int i = threadIdx.x; i < vLen; i += 512) hv[i] = 0;
  __syncthreads();
  int m4 = M >> 2;
  int per = (m4 + NCH - 1) / NCH;
  int i0 = c * per, i1 = min(i0 + per, m4);
  for (int i = i0 + threadIdx.x; i < i1; i += 512) {
    int4 ek = ((const int4*)edges)[i];
    int4 vk = ((const int4*)vertex)[i];
    if (ek.x >= eLo && ek.x < eHi) atomicAdd(&he[ek.x - eLo], 1);
    if (ek.y >= eLo && ek.y < eHi) atomicAdd(&he[ek.y - eLo], 1);
    if (ek.z >= eLo && ek.z < eHi) atomicAdd(&he[ek.z - eLo], 1);
    if (ek.w >= eLo && ek.w < eHi) atomicAdd(&he[ek.w - eLo], 1);
    if (vk.x >= vLo && vk.x < vHi) atomicAdd(&hv[vk.x - vLo], 1);
    if (vk.y >= vLo && vk.y < vHi) atomicAdd(&hv[vk.y - vLo], 1);
    if (vk.z >= vLo && vk.z < vHi) atomicAdd(&hv[vk.z - vLo], 1);
    if (vk.w >= vLo && vk.w < vHi) atomicAdd(&hv[vk.w - vLo], 1);
  }
  if (c == NCH - 1) {  // scalar tail if M % 4 != 0
    for (int m = (m4 << 2) + threadIdx.x; m < M; m += 512) {
      int e = edges[m], v = vertex[m];
      if (e >= eLo && e < eHi) atomicAdd(&he[e - eLo], 1);
      if (v >= vLo && v < vHi) atomicAdd(&hv[v - vLo], 1);
    }
  }
  __syncthreads();
  // dense table writes (no atomics)
  for (int i = threadIdx.x; i < eLen; i += 512) T_E[(size_t)c * E + eLo + i] = he[i];
  for (int i = threadIdx.x; i < vLen; i += 512) T_V[(size_t)c * N + vLo + i] = hv[i];
}

// ------- per-id prefix over chunks: T -> per-chunk bases (in place) --------
__global__ __launch_bounds__(256) void chunk_prefix(
    int* __restrict__ T_E, int* __restrict__ C_E, int E,
    int* __restrict__ T_V, int* __restrict__ C_V, int N) {
  int stride = gridDim.x * 256;
  int total = E + N;
  for (int i = blockIdx.x * 256 + threadIdx.x; i < total; i += stride) {
    if (i < E) {
      int run = 0;
      #pragma unroll
      for (int c = 0; c < NCH; ++c) {
        int t = T_E[(size_t)c * E + i];
        T_E[(size_t)c * E + i] = run;
        run += t;
      }
      C_E[i] = run;
    } else {
      int id = i - E;
      int run = 0;
      #pragma unroll
      for (int c = 0; c < NCH; ++c) {
        int t = T_V[(size_t)c * N + id];
        T_V[(size_t)c * N + id] = run;
        run += t;
      }
      C_V[id] = run;
    }
  }
}

// ---------------- hierarchical exclusive scan ------------------------------
__device__ __forceinline__ int block_exscan(int x, int tid, int* wsum) {
  int lane = tid & 63, w = tid >> 6;
  int v = x;
  #pragma unroll
  for (int off = 1; off < 64; off <<= 1) {
    int t = __shfl_up(v, off);
    if (lane >= off) v += t;
  }
  if (lane == 63) wsum[w] = v;
  __syncthreads();
  if (w == 0 && lane < 16) {
    int s = wsum[lane];
    #pragma unroll
    for (int off = 1; off < 16; off <<= 1) {
      int t = __shfl_up(s, off);
      if (lane >= off) s += t;
    }
    wsum[lane] = s;
  }
  __syncthreads();
  int woff = (w == 0) ? 0 : wsum[w - 1];
  return woff + v - x;
}

__global__ __launch_bounds__(1024) void scan_local(
    const int* __restrict__ C_E, int* __restrict__ A_E, int lenE,
    const int* __restrict__ C_V, int* __restrict__ A_V, int lenN,
    int* __restrict__ sums, int BE) {
  __shared__ int wsum[16];
  int b = blockIdx.x;
  const int* C = (b < BE) ? C_E : C_V;
  int* A = (b < BE) ? A_E : A_V;
  int len = (b < BE) ? lenE : lenN;
  int base = ((b < BE) ? b : (b - BE)) << 10;
  int i = base + threadIdx.x;
  int x = (i < len) ? C[i] : 0;
  int ex = block_exscan(x, threadIdx.x, wsum);
  if (i < len) A[i] = ex;
  if (threadIdx.x == 0) sums[b] = wsum[15];
}

__global__ __launch_bounds__(1024) void scan_sums(int* __restrict__ sums, int BE, int BV) {
  __shared__ int wsum[16];
  int off = (blockIdx.x == 0) ? 0 : BE;
  int len = (blockIdx.x == 0) ? BE : BV;
  int x = (threadIdx.x < len) ? sums[off + threadIdx.x] : 0;
  int ex = block_exscan(x, threadIdx.x, wsum);
  if (threadIdx.x < len) sums[off + threadIdx.x] = ex;
}

__global__ __launch_bounds__(1024) void scan_add(
    int* __restrict__ A_E, int lenE, int* __restrict__ A_V, int lenN,
    const int* __restrict__ sums, int BE) {
  int b = blockIdx.x;
  int* A = (b < BE) ? A_E : A_V;
  int len = (b < BE) ? lenE : lenN;
  int base = ((b < BE) ? b : (b - BE)) << 10;
  int i = base + threadIdx.x;
  if (i < len) A[i] += sums[b];
}

// ------- scatter: deterministic slots, LDS-only ranking (no global atomics)
__global__ __launch_bounds__(512) void scatter_tab(
    const int* __restrict__ edges, const int* __restrict__ vertex,
    const int* __restrict__ A_E, const int* __restrict__ A_V,
    const int* __restrict__ T_E, const int* __restrict__ T_V,
    int* __restrict__ colE, int* __restrict__ colV, int E, int N, int M) {
  __shared__ int offE[RE_SL];
  __shared__ int curE[RE_SL];
  __shared__ int offV[RV_SL];
  __shared__ int curV[RV_SL];
  int b = blockIdx.x;
  int r = b & (NRR - 1), c = b >> 4;
  int RE = (E + NRR - 1) / NRR, RV = (N + NRR - 1) / NRR;
  int eLo = r * RE, eHi = min(eLo + RE, E);
  int vLo = r * RV, vHi = min(vLo + RV, N);
  int eLen = eHi - eLo, vLen = vHi - vLo;
  for (int i = threadIdx.x; i < eLen; i += 512) {
    offE[i] = A_E[eLo + i] + T_E[(size_t)c * E + eLo + i];
    curE[i] = 0;
  }
  for (int i = threadIdx.x; i < vLen; i += 512) {
    offV[i] = A_V[vLo + i] + T_V[(size_t)c * N + vLo + i];
    curV[i] = 0;
  }
  __syncthreads();
  int m4 = M >> 2;
  int per = (m4 + NCH - 1) / NCH;
  int i0 = c * per, i1 = min(i0 + per, m4);
  for (int i = i0 + threadIdx.x; i < i1; i += 512) {
    int4 ek = ((const int4*)edges)[i];
    int4 vk = ((const int4*)vertex)[i];
    int es[4] = {ek.x, ek.y, ek.z, ek.w};
    int vs[4] = {vk.x, vk.y, vk.z, vk.w};
    #pragma unroll
    for (int t = 0; t < 4; ++t) {
      if (es[t] >= eLo && es[t] < eHi) {
        int p = atomicAdd(&curE[es[t] - eLo], 1);
        colE[offE[es[t] - eLo] + p] = vs[t];
      }
      if (vs[t] >= vLo && vs[t] < vHi) {
        int p = atomicAdd(&curV[vs[t] - vLo], 1);
        colV[offV[vs[t] - vLo] + p] = es[t];
      }
    }
  }
  if (c == NCH - 1) {
    for (int m = (m4 << 2) + threadIdx.x; m < M; m += 512) {
      int e = edges[m], v = vertex[m];
      if (e >= eLo && e < eHi) {
        int p = atomicAdd(&curE[e - eLo], 1);
        colE[offE[e - eLo] + p] = v;
      }
      if (v >= vLo && v < vHi) {
        int p = atomicAdd(&curV[v - vLo], 1);
        colV[offV[v - vLo] + p] = e;
      }
    }
  }
}

// ---------------- stage 1: vertex->edge mean (fp16, parity, batch tail) ----
__global__ __launch_bounds__(256) void edge_agg_h2(
    const uint2* __restrict__ Xh, const float* __restrict__ degE,
    const int* __restrict__ A_E, const int* __restrict__ C_E,
    const int* __restrict__ colE, uint2* __restrict__ Xe_h, int E) {
  int eid = blockIdx.x * 4 + (threadIdx.x >> 6);
  int lane = threadIdx.x & 63;
  if (eid >= E) return;
  int s = A_E[eid], cnt = C_E[eid], e = s + cnt;
  int half = lane >> 5, fl = lane & 31;
  __half2 accA = u2h(0u), accB = u2h(0u);
  int idx = s;
  for (; idx + 8 <= e; idx += 8) {
    int ra = colE[idx + 0 + half];
    int rb = colE[idx + 2 + half];
    int rc = colE[idx + 4 + half];
    int rd = colE[idx + 6 + half];
    uint2 va = Xh[(size_t)ra * 32 + fl];
    uint2 vb = Xh[(size_t)rb * 32 + fl];
    uint2 vc = Xh[(size_t)rc * 32 + fl];
    uint2 vd = Xh[(size_t)rd * 32 + fl];
    accA = __hadd2(accA, __hadd2(__hadd2(u2h(va.x), u2h(vb.x)), __hadd2(u2h(vc.x), u2h(vd.x))));
    accB = __hadd2(accB, __hadd2(__hadd2(u2h(va.y), u2h(vb.y)), __hadd2(u2h(vc.y), u2h(vd.y))));
  }
  int rem = e - idx;
  if (rem > 0) {
    int r[4];
    #pragma unroll
    for (int t = 0; t < 4; ++t) {
      int p = 2 * t + half;
      r[t] = colE[idx + (p < rem ? p : 0)];
    }
    #pragma unroll
    for (int t = 0; t < 4; ++t) {
      uint2 v = Xh[(size_t)r[t] * 32 + fl];
      if (2 * t + half < rem) {
        accA = __hadd2(accA, u2h(v.x));
        accB = __hadd2(accB, u2h(v.y));
      }
    }
  }
  float2 fA = __half22float2(accA), fB = __half22float2(accB);
  float t0 = fA.x, t1 = fA.y, t2 = fB.x, t3 = fB.y;
  t0 += __shfl_xor(t0, 32);
  t1 += __shfl_xor(t1, 32);
  t2 += __shfl_xor(t2, 32);
  t3 += __shfl_xor(t3, 32);
  if (lane < 32) {
    float scale = degE[eid] / fmaxf((float)cnt, 1.0f);
    __half2 h0 = __float22half2_rn(make_float2(t0 * scale, t1 * scale));
    __half2 h1 = __float22half2_rn(make_float2(t2 * scale, t3 * scale));
    Xe_h[(size_t)eid * 32 + fl] =
        make_uint2(__builtin_bit_cast(unsigned, h0), __builtin_bit_cast(unsigned, h1));
  }
}

// ---------------- stage 2: edge->vertex sum + LN + combine -----------------
__global__ __launch_bounds__(256) void vertex_ln_h(
    const uint2* __restrict__ Xe_h, const float* __restrict__ X0,
    const float* __restrict__ degV, const float* __restrict__ ln_w,
    const float* __restrict__ ln_b, const float* __restrict__ alpha_p,
    const int* __restrict__ A_V, const int* __restrict__ C_V,
    const int* __restrict__ colV, ushort* __restrict__ Xi_bf, int N) {
  int fl = threadIdx.x & 31;
  int n = blockIdx.x * 8 + (threadIdx.x >> 5);
  if (n >= N) return;
  int s = A_V[n], cnt = C_V[n];
  __half2 accA = u2h(0u), accB = u2h(0u);
  int idx = s, rem = cnt;
  while (rem > 0) {
    int r[8];
    #pragma unroll
    for (int t = 0; t < 8; ++t) r[t] = colV[idx + (t < rem ? t : 0)];
    #pragma unroll
    for (int t = 0; t < 8; ++t) {
      uint2 v = Xe_h[(size_t)r[t] * 32 + fl];
      if (t < rem) {
        accA = __hadd2(accA, u2h(v.x));
        accB = __hadd2(accB, u2h(v.y));
      }
    }
    idx += 8;
    rem -= 8;
  }
  float2 fA = __half22float2(accA), fB = __half22float2(accB);
  float t0 = fA.x, t1 = fA.y, t2 = fB.x, t3 = fB.y;
  float sm = (t0 + t1) + (t2 + t3);
  float q = t0 * t0 + t1 * t1 + t2 * t2 + t3 * t3;
  #pragma unroll
  for (int off = 1; off < 32; off <<= 1) {
    sm += __shfl_xor(sm, off);
    q += __shfl_xor(q, off);
  }
  float dv = degV[n];
  float csc = 2.f * dv;
  float mu = csc * sm * (1.f / 128.f);
  float var = csc * csc * q * (1.f / 128.f) - mu * mu;
  float rstd = rsqrtf(var + 1e-5f);
  f32x4 lw = ((const f32x4*)ln_w)[fl];
  f32x4 lb = ((const f32x4*)ln_b)[fl];
  f32x4 x0 = ((const f32x4*)X0)[(size_t)n * 32 + fl];
  float alpha = *alpha_p;
  float tt[4] = {t0, t1, t2, t3};
  ushort ob[4];
  #pragma unroll
  for (int i = 0; i < 4; ++i) {
    float xh = csc * tt[i];
    float xn = (xh - mu) * rstd * lw[i] + lb[i];
    float xi = (1.f - alpha) * xn + alpha * x0[i];
    __hip_bfloat16 bb = __float2bfloat16(xi);
    ob[i] = __builtin_bit_cast(ushort, bb);
  }
  unsigned u0 = (unsigned)ob[0] | ((unsigned)ob[1] << 16);
  unsigned u1 = (unsigned)ob[2] | ((unsigned)ob[3] << 16);
  ((uint2*)Xi_bf)[(size_t)n * 32 + fl] = make_uint2(u0, u1);
}

// ---------------- Weff = beta*W^T + (1-beta)*I, bf16, stored [j][k] -------
__global__ void wprep_kernel(const float* __restrict__ W, const float* __restrict__ beta_p,
                             ushort* __restrict__ Wbf) {
  int idx = blockIdx.x * 256 + threadIdx.x;
  int j = idx >> 7, k = idx & 127;
  float beta = *beta_p;
  float v = beta * W[idx] + ((j == k) ? (1.f - beta) : 0.f);
  __hip_bfloat16 b = __float2bfloat16(v);
  Wbf[idx] = *(ushort*)&b;
}

// ---------------- stage 3: out = Xi @ Weff via MFMA bf16 ------------------
__global__ __launch_bounds__(256) void gemm_out(
    const ushort* __restrict__ Xi_bf, const ushort* __restrict__ Wbf,
    float* __restrict__ out, int N) {
  __shared__ __align__(16) ushort Wl[128 * 128];
  for (int t = threadIdx.x; t < 2048; t += 256) {
    int j = t >> 4, chunk = t & 15;
    bf16x8 v = ((const bf16x8*)Wbf)[t];
    ((bf16x8*)Wl)[j * 16 + (chunk ^ (j & 7))] = v;
  }
  __syncthreads();
  int wv = threadIdx.x >> 6, lane = threadIdx.x & 63;
  int row0 = blockIdx.x * 128 + wv * 32;
  f32x4 acc[2][8] = {};
  #pragma unroll
  for (int ks = 0; ks < 4; ++ks) {
    bf16x8 a[2];
    #pragma unroll
    for (int rt = 0; rt < 2; ++rt) {
      int row = row0 + rt * 16 + (lane & 15);
      row = row < N ? row : N - 1;
      a[rt] = *(const bf16x8*)(Xi_bf + (size_t)row * 128 + ks * 32 + (lane >> 4) * 8);
    }
    int chunk = ks * 4 + (lane >> 4);
    #pragma unroll
    for (int c = 0; c < 8; ++c) {
      int col = c * 16 + (lane & 15);
      bf16x8 bb = ((const bf16x8*)Wl)[col * 16 + (chunk ^ (col & 7))];
      acc[0][c] = __builtin_amdgcn_mfma_f32_16x16x32_bf16(a[0], bb, acc[0][c], 0, 0, 0);
      acc[1][c] = __builtin_amdgcn_mfma_f32_16x16x32_bf16(a[1], bb, acc[1][c], 0, 0, 0);
    }
  }
  #pragma unroll
  for (int rt = 0; rt < 2; ++rt) {
    #pragma unroll
    for (int c = 0; c < 8; ++c) {
      #pragma unroll
      for (int i = 0; i < 4; ++i) {
        int row = row0 + rt * 16 + (lane >> 4) * 4 + i;
        int col = c * 16 + (lane & 15);
        if (row < N) out[(size_t)row * 128 + col] = acc[rt][c][i];
      }
    }
  }
}

extern "C" void kernel_launch(void* const* d_in, const int* in_sizes, int n_in,
                              void* d_out, int out_size, void* d_ws, size_t ws_size,
                              hipStream_t stream) {
  const float* X     = (const float*)d_in[0];
  const float* X0    = (const float*)d_in[1];
  const float* degE  = (const float*)d_in[2];
  const float* degV  = (const float*)d_in[3];
  const float* W     = (const float*)d_in[4];
  const float* alpha = (const float*)d_in[5];
  const float* beta  = (const float*)d_in[6];
  const float* lnw   = (const float*)d_in[7];
  const float* lnb   = (const float*)d_in[8];
  const int* vertex  = (const int*)d_in[9];
  const int* edges   = (const int*)d_in[10];

  const int N = in_sizes[0] / D;
  const int E = in_sizes[2];
  const int M = in_sizes[9];

  const int BE = (E + 1023) >> 10;
  const int BV = (N + 1023) >> 10;

  char* p = (char*)d_ws;
  auto alloc = [&](size_t bytes) { char* r = p; p += (bytes + 255) & ~255ull; return r; };
  int* A_E  = (int*)alloc((size_t)E * 4);
  int* A_V  = (int*)alloc((size_t)N * 4);
  int* C_E  = (int*)alloc((size_t)E * 4);
  int* C_V  = (int*)alloc((size_t)N * 4);
  int* sums = (int*)alloc(1024);
  int* colE = (int*)alloc((size_t)M * 4);
  int* colV = (int*)alloc((size_t)M * 4);
  int* T_E  = (int*)alloc((size_t)NCH * E * 4);
  int* T_V  = (int*)alloc((size_t)NCH * N * 4);
  uint2* X_h  = (uint2*)alloc((size_t)N * D * 2);      // N x 128 fp16
  uint2* Xe_h = (uint2*)alloc((size_t)E * D * 2);      // E x 128 fp16
  ushort* Wbf = (ushort*)alloc(16384 * 2);
  ushort* Xi_bf = (ushort*)X_h;  // X_h dead after edge_agg_h2; alias

  count_tab<<<NRR * NCH + CVT_BLOCKS, 512, 0, stream>>>(
      edges, vertex, T_E, T_V, E, N, M, X, X_h, N * D / 4);
  chunk_prefix<<<512, 256, 0, stream>>>(T_E, C_E, E, T_V, C_V, N);
  scan_local<<<BE + BV, 1024, 0, stream>>>(C_E, A_E, E, C_V, A_V, N, sums, BE);
  scan_sums<<<2, 1024, 0, stream>>>(sums, BE, BV);
  scan_add<<<BE + BV, 1024, 0, stream>>>(A_E, E, A_V, N, sums, BE);
  scatter_tab<<<NRR * NCH, 512, 0, stream>>>(edges, vertex, A_E, A_V, T_E, T_V,
                                             colE, colV, E, N, M);
  edge_agg_h2<<<(E + 3) / 4, 256, 0, stream>>>(X_h, degE, A_E, C_E, colE, Xe_h, E);
  vertex_ln_h<<<(N + 7) / 8, 256, 0, stream>>>(Xe_h, X0, degV, lnw, lnb, alpha,
                                               A_V, C_V, colV, Xi_bf, N);
  wprep_kernel<<<64, 256, 0, stream>>>(W, beta, Wbf);
  gemm_out<<<(N + 127) / 128, 256, 0, stream>>>(Xi_bf, Wbf, (float*)d_out, N);
}

// Round 9
// 135.807 us; speedup vs baseline: 1.5806x; 1.0565x over previous
//
#include <hip/hip_runtime.h>
#include <hip/hip_fp16.h>
#include <hip/hip_bf16.h>

#define D 128
#define NRR 16      // ranges (2 per XCD under blockIdx%8 round-robin)
#define NCH 32      // chunks per range
#define CVT_BLOCKS 512
#define RE_SL 1600   // >= ceil(E/16)
#define RV_SL 6272   // >= ceil(N/16)

typedef __attribute__((ext_vector_type(8))) short bf16x8;
typedef __attribute__((ext_vector_type(4))) float f32x4;

__device__ __forceinline__ __half2 u2h(unsigned u) { return __builtin_bit_cast(__half2, u); }
__device__ __forceinline__ unsigned pack_h2(float a, float b) {
  __half2 h = __float22half2_rn(make_float2(a, b));
  return __builtin_bit_cast(unsigned, h);
}
__device__ __forceinline__ ushort f2bf(float x) {
  __hip_bfloat16 b = __float2bfloat16(x);
  return __builtin_bit_cast(ushort, b);
}

// ------- count: per-(range,chunk) LDS histograms -> dense tables; + cvt ----
__global__ __launch_bounds__(512) void count_tab(
    const int* __restrict__ edges, const int* __restrict__ vertex,
    int* __restrict__ T_E, int* __restrict__ T_V, int E, int N, int M,
    const float* __restrict__ X, uint2* __restrict__ Xh, int xn4) {
  __shared__ int he[RE_SL];
  __shared__ int hv[RV_SL];
  int b = blockIdx.x;
  if (b >= NRR * NCH) {
    const f32x4* X4 = (const f32x4*)X;
    int stride = (gridDim.x - NRR * NCH) * 512;
    for (int i = (b - NRR * NCH) * 512 + threadIdx.x; i < xn4; i += stride) {
      f32x4 v = X4[i];
      Xh[i] = make_uint2(pack_h2(v[0], v[1]), pack_h2(v[2], v[3]));
    }
    return;
  }
  int r = b & (NRR - 1), c = b >> 4;
  int RE = (E + NRR - 1) / NRR, RV = (N + NRR - 1) / NRR;
  int eLo = r * RE, eHi = min(eLo + RE, E);
  int vLo = r * RV, vHi = min(vLo + RV, N);
  int eLen = eHi - eLo, vLen = vHi - vLo;
  for (int i = threadIdx.x; i < eLen; i += 512) he[i] = 0;
  for (int i = threadIdx.x; i < vLen; i += 512) hv[i] = 0;
  __syncthreads();
  int m4 = M >> 2;
  int per = (m4 + NCH - 1) / NCH;
  int i0 = c * per, i1 = min(i0 + per, m4);
  for (int i = i0 + threadIdx.x; i < i1; i += 512) {
    int4 ek = ((const int4*)edges)[i];
    int4 vk = ((const int4*)vertex)[i];
    if (ek.x >= eLo && ek.x < eHi) atomicAdd(&he[ek.x - eLo], 1);
    if (ek.y >= eLo && ek.y < eHi) atomicAdd(&he[ek.y - eLo], 1);
    if (ek.z >= eLo && ek.z < eHi) atomicAdd(&he[ek.z - eLo], 1);
    if (ek.w >= eLo && ek.w < eHi) atomicAdd(&he[ek.w - eLo], 1);
    if (vk.x >= vLo && vk.x < vHi) atomicAdd(&hv[vk.x - vLo], 1);
    if (vk.y >= vLo && vk.y < vHi) atomicAdd(&hv[vk.y - vLo], 1);
    if (vk.z >= vLo && vk.z < vHi) atomicAdd(&hv[vk.z - vLo], 1);
    if (vk.w >= vLo && vk.w < vHi) atomicAdd(&hv[vk.w - vLo], 1);
  }
  if (c == NCH - 1) {
    for (int m = (m4 << 2) + threadIdx.x; m < M; m += 512) {
      int e = edges[m], v = vertex[m];
      if (e >= eLo && e < eHi) atomicAdd(&he[e - eLo], 1);
      if (v >= vLo && v < vHi) atomicAdd(&hv[v - vLo], 1);
    }
  }
  __syncthreads();
  for (int i = threadIdx.x; i < eLen; i += 512) T_E[(size_t)c * E + eLo + i] = he[i];
  for (int i = threadIdx.x; i < vLen; i += 512) T_V[(size_t)c * N + vLo + i] = hv[i];
}

// ------- per-id prefix over chunks: T -> per-chunk bases (in place) --------
__global__ __launch_bounds__(256) void chunk_prefix(
    int* __restrict__ T_E, int* __restrict__ C_E, int E,
    int* __restrict__ T_V, int* __restrict__ C_V, int N) {
  int stride = gridDim.x * 256;
  int total = E + N;
  for (int i = blockIdx.x * 256 + threadIdx.x; i < total; i += stride) {
    if (i < E) {
      int run = 0;
      #pragma unroll
      for (int c = 0; c < NCH; ++c) {
        int t = T_E[(size_t)c * E + i];
        T_E[(size_t)c * E + i] = run;
        run += t;
      }
      C_E[i] = run;
    } else {
      int id = i - E;
      int run = 0;
      #pragma unroll
      for (int c = 0; c < NCH; ++c) {
        int t = T_V[(size_t)c * N + id];
        T_V[(size_t)c * N + id] = run;
        run += t;
      }
      C_V[id] = run;
    }
  }
}

// ---------------- hierarchical exclusive scan ------------------------------
__device__ __forceinline__ int block_exscan(int x, int tid, int* wsum) {
  int lane = tid & 63, w = tid >> 6;
  int v = x;
  #pragma unroll
  for (int off = 1; off < 64; off <<= 1) {
    int t = __shfl_up(v, off);
    if (lane >= off) v += t;
  }
  if (lane == 63) wsum[w] = v;
  __syncthreads();
  if (w == 0 && lane < 16) {
    int s = wsum[lane];
    #pragma unroll
    for (int off = 1; off < 16; off <<= 1) {
      int t = __shfl_up(s, off);
      if (lane >= off) s += t;
    }
    wsum[lane] = s;
  }
  __syncthreads();
  int woff = (w == 0) ? 0 : wsum[w - 1];
  return woff + v - x;
}

__global__ __launch_bounds__(1024) void scan_local(
    const int* __restrict__ C_E, int* __restrict__ A_E, int lenE,
    const int* __restrict__ C_V, int* __restrict__ A_V, int lenN,
    int* __restrict__ sums, int BE) {
  __shared__ int wsum[16];
  int b = blockIdx.x;
  const int* C = (b < BE) ? C_E : C_V;
  int* A = (b < BE) ? A_E : A_V;
  int len = (b < BE) ? lenE : lenN;
  int base = ((b < BE) ? b : (b - BE)) << 10;
  int i = base + threadIdx.x;
  int x = (i < len) ? C[i] : 0;
  int ex = block_exscan(x, threadIdx.x, wsum);
  if (i < len) A[i] = ex;
  if (threadIdx.x == 0) sums[b] = wsum[15];
}

__global__ __launch_bounds__(1024) void scan_sums(int* __restrict__ sums, int BE, int BV) {
  __shared__ int wsum[16];
  int off = (blockIdx.x == 0) ? 0 : BE;
  int len = (blockIdx.x == 0) ? BE : BV;
  int x = (threadIdx.x < len) ? sums[off + threadIdx.x] : 0;
  int ex = block_exscan(x, threadIdx.x, wsum);
  if (threadIdx.x < len) sums[off + threadIdx.x] = ex;
}

__global__ __launch_bounds__(1024) void scan_add(
    int* __restrict__ A_E, int lenE, int* __restrict__ A_V, int lenN,
    const int* __restrict__ sums, int BE) {
  int b = blockIdx.x;
  int* A = (b < BE) ? A_E : A_V;
  int len = (b < BE) ? lenE : lenN;
  int base = ((b < BE) ? b : (b - BE)) << 10;
  int i = base + threadIdx.x;
  if (i < len) A[i] += sums[b];
}

// ------- scatter: deterministic slots, LDS-only ranking --------------------
__global__ __launch_bounds__(512) void scatter_tab(
    const int* __restrict__ edges, const int* __restrict__ vertex,
    const int* __restrict__ A_E, const int* __restrict__ A_V,
    const int* __restrict__ T_E, const int* __restrict__ T_V,
    int* __restrict__ colE, int* __restrict__ colV, int E, int N, int M) {
  __shared__ int offE[RE_SL];
  __shared__ int curE[RE_SL];
  __shared__ int offV[RV_SL];
  __shared__ int curV[RV_SL];
  int b = blockIdx.x;
  int r = b & (NRR - 1), c = b >> 4;
  int RE = (E + NRR - 1) / NRR, RV = (N + NRR - 1) / NRR;
  int eLo = r * RE, eHi = min(eLo + RE, E);
  int vLo = r * RV, vHi = min(vLo + RV, N);
  int eLen = eHi - eLo, vLen = vHi - vLo;
  for (int i = threadIdx.x; i < eLen; i += 512) {
    offE[i] = A_E[eLo + i] + T_E[(size_t)c * E + eLo + i];
    curE[i] = 0;
  }
  for (int i = threadIdx.x; i < vLen; i += 512) {
    offV[i] = A_V[vLo + i] + T_V[(size_t)c * N + vLo + i];
    curV[i] = 0;
  }
  __syncthreads();
  int m4 = M >> 2;
  int per = (m4 + NCH - 1) / NCH;
  int i0 = c * per, i1 = min(i0 + per, m4);
  for (int i = i0 + threadIdx.x; i < i1; i += 512) {
    int4 ek = ((const int4*)edges)[i];
    int4 vk = ((const int4*)vertex)[i];
    int es[4] = {ek.x, ek.y, ek.z, ek.w};
    int vs[4] = {vk.x, vk.y, vk.z, vk.w};
    #pragma unroll
    for (int t = 0; t < 4; ++t) {
      if (es[t] >= eLo && es[t] < eHi) {
        int p = atomicAdd(&curE[es[t] - eLo], 1);
        colE[offE[es[t] - eLo] + p] = vs[t];
      }
      if (vs[t] >= vLo && vs[t] < vHi) {
        int p = atomicAdd(&curV[vs[t] - vLo], 1);
        colV[offV[vs[t] - vLo] + p] = es[t];
      }
    }
  }
  if (c == NCH - 1) {
    for (int m = (m4 << 2) + threadIdx.x; m < M; m += 512) {
      int e = edges[m], v = vertex[m];
      if (e >= eLo && e < eHi) {
        int p = atomicAdd(&curE[e - eLo], 1);
        colE[offE[e - eLo] + p] = v;
      }
      if (v >= vLo && v < vHi) {
        int p = atomicAdd(&curV[v - vLo], 1);
        colV[offV[v - vLo] + p] = e;
      }
    }
  }
}

// ---------------- stage 1: vertex->edge mean, quarter-wave, fp32 accum -----
// 16 lanes per edge; lane owns 8 features (uint4 = 16B); 16-deep gather batch
__global__ __launch_bounds__(256) void edge_agg_q(
    const uint4* __restrict__ Xh4, const float* __restrict__ degE,
    const int* __restrict__ A_E, const int* __restrict__ C_E,
    const int* __restrict__ colE, uint4* __restrict__ Xe4, int E) {
  int ql = threadIdx.x & 15;
  int eid = blockIdx.x * 16 + (threadIdx.x >> 4);
  if (eid >= E) return;
  int s = A_E[eid], cnt = C_E[eid];
  float f0 = 0.f, f1 = 0.f, f2 = 0.f, f3 = 0.f, f4 = 0.f, f5 = 0.f, f6 = 0.f, f7 = 0.f;
  int idx = s, rem = cnt;
  while (rem > 0) {
    int r[16];
    #pragma unroll
    for (int t = 0; t < 16; ++t) r[t] = colE[idx + (t < rem ? t : 0)];
    #pragma unroll
    for (int t = 0; t < 16; ++t) {
      uint4 v = Xh4[(size_t)r[t] * 16 + ql];
      if (t < rem) {
        float2 p0 = __half22float2(u2h(v.x));
        float2 p1 = __half22float2(u2h(v.y));
        float2 p2 = __half22float2(u2h(v.z));
        float2 p3 = __half22float2(u2h(v.w));
        f0 += p0.x; f1 += p0.y; f2 += p1.x; f3 += p1.y;
        f4 += p2.x; f5 += p2.y; f6 += p3.x; f7 += p3.y;
      }
    }
    idx += 16;
    rem -= 16;
  }
  float scale = degE[eid] / fmaxf((float)cnt, 1.0f);
  uint4 o;
  o.x = pack_h2(f0 * scale, f1 * scale);
  o.y = pack_h2(f2 * scale, f3 * scale);
  o.z = pack_h2(f4 * scale, f5 * scale);
  o.w = pack_h2(f6 * scale, f7 * scale);
  Xe4[(size_t)eid * 16 + ql] = o;
}

// ---------------- stage 2: edge->vertex sum + LN + combine, quarter-wave ---
// 16 lanes per vertex; lane owns 8 features; 8-deep predicated batches
__global__ __launch_bounds__(256) void vertex_ln_q(
    const uint4* __restrict__ Xe4, const float* __restrict__ X0,
    const float* __restrict__ degV, const float* __restrict__ ln_w,
    const float* __restrict__ ln_b, const float* __restrict__ alpha_p,
    const int* __restrict__ A_V, const int* __restrict__ C_V,
    const int* __restrict__ colV, uint4* __restrict__ Xi4, int N) {
  int ql = threadIdx.x & 15;
  int n = blockIdx.x * 16 + (threadIdx.x >> 4);
  if (n >= N) return;
  int s = A_V[n], cnt = C_V[n];
  float f0 = 0.f, f1 = 0.f, f2 = 0.f, f3 = 0.f, f4 = 0.f, f5 = 0.f, f6 = 0.f, f7 = 0.f;
  int idx = s, rem = cnt;
  while (rem > 0) {
    int r[8];
    #pragma unroll
    for (int t = 0; t < 8; ++t) r[t] = colV[idx + (t < rem ? t : 0)];
    #pragma unroll
    for (int t = 0; t < 8; ++t) {
      uint4 v = Xe4[(size_t)r[t] * 16 + ql];
      if (t < rem) {
        float2 p0 = __half22float2(u2h(v.x));
        float2 p1 = __half22float2(u2h(v.y));
        float2 p2 = __half22float2(u2h(v.z));
        float2 p3 = __half22float2(u2h(v.w));
        f0 += p0.x; f1 += p0.y; f2 += p1.x; f3 += p1.y;
        f4 += p2.x; f5 += p2.y; f6 += p3.x; f7 += p3.y;
      }
    }
    idx += 8;
    rem -= 8;
  }
  float sm = ((f0 + f1) + (f2 + f3)) + ((f4 + f5) + (f6 + f7));
  float qq = ((f0 * f0 + f1 * f1) + (f2 * f2 + f3 * f3)) +
             ((f4 * f4 + f5 * f5) + (f6 * f6 + f7 * f7));
  #pragma unroll
  for (int off = 1; off < 16; off <<= 1) {  // reduce across the 16-lane quarter
    sm += __shfl_xor(sm, off);
    qq += __shfl_xor(qq, off);
  }
  float dv = degV[n];
  float csc = 2.f * dv;
  float mu = csc * sm * (1.f / 128.f);
  float var = csc * csc * qq * (1.f / 128.f) - mu * mu;
  float rstd = rsqrtf(var + 1e-5f);
  const f32x4* lw4 = (const f32x4*)ln_w;
  const f32x4* lb4 = (const f32x4*)ln_b;
  const f32x4* X04 = (const f32x4*)X0;
  f32x4 lwa = lw4[ql * 2], lwb = lw4[ql * 2 + 1];
  f32x4 lba = lb4[ql * 2], lbb = lb4[ql * 2 + 1];
  f32x4 x0a = X04[(size_t)n * 32 + ql * 2], x0b = X04[(size_t)n * 32 + ql * 2 + 1];
  float alpha = *alpha_p;
  float ff[8] = {f0, f1, f2, f3, f4, f5, f6, f7};
  float lww[8] = {lwa[0], lwa[1], lwa[2], lwa[3], lwb[0], lwb[1], lwb[2], lwb[3]};
  float lbb_[8] = {lba[0], lba[1], lba[2], lba[3], lbb[0], lbb[1], lbb[2], lbb[3]};
  float x00[8] = {x0a[0], x0a[1], x0a[2], x0a[3], x0b[0], x0b[1], x0b[2], x0b[3]};
  ushort ob[8];
  #pragma unroll
  for (int i = 0; i < 8; ++i) {
    float xh = csc * ff[i];
    float xn = (xh - mu) * rstd * lww[i] + lbb_[i];
    float xi = (1.f - alpha) * xn + alpha * x00[i];
    ob[i] = f2bf(xi);
  }
  uint4 o;
  o.x = (unsigned)ob[0] | ((unsigned)ob[1] << 16);
  o.y = (unsigned)ob[2] | ((unsigned)ob[3] << 16);
  o.z = (unsigned)ob[4] | ((unsigned)ob[5] << 16);
  o.w = (unsigned)ob[6] | ((unsigned)ob[7] << 16);
  Xi4[(size_t)n * 16 + ql] = o;
}

// ---------------- Weff = beta*W^T + (1-beta)*I, bf16, stored [j][k] -------
__global__ void wprep_kernel(const float* __restrict__ W, const float* __restrict__ beta_p,
                             ushort* __restrict__ Wbf) {
  int idx = blockIdx.x * 256 + threadIdx.x;
  int j = idx >> 7, k = idx & 127;
  float beta = *beta_p;
  float v = beta * W[idx] + ((j == k) ? (1.f - beta) : 0.f);
  Wbf[idx] = f2bf(v);
}

// ---------------- stage 3: out = Xi @ Weff via MFMA bf16 ------------------
__global__ __launch_bounds__(256) void gemm_out(
    const ushort* __restrict__ Xi_bf, const ushort* __restrict__ Wbf,
    float* __restrict__ out, int N) {
  __shared__ __align__(16) ushort Wl[128 * 128];
  for (int t = threadIdx.x; t < 2048; t += 256) {
    int j = t >> 4, chunk = t & 15;
    bf16x8 v = ((const bf16x8*)Wbf)[t];
    ((bf16x8*)Wl)[j * 16 + (chunk ^ (j & 7))] = v;
  }
  __syncthreads();
  int wv = threadIdx.x >> 6, lane = threadIdx.x & 63;
  int row0 = blockIdx.x * 128 + wv * 32;
  f32x4 acc[2][8] = {};
  #pragma unroll
  for (int ks = 0; ks < 4; ++ks) {
    bf16x8 a[2];
    #pragma unroll
    for (int rt = 0; rt < 2; ++rt) {
      int row = row0 + rt * 16 + (lane & 15);
      row = row < N ? row : N - 1;
      a[rt] = *(const bf16x8*)(Xi_bf + (size_t)row * 128 + ks * 32 + (lane >> 4) * 8);
    }
    int chunk = ks * 4 + (lane >> 4);
    #pragma unroll
    for (int c = 0; c < 8; ++c) {
      int col = c * 16 + (lane & 15);
      bf16x8 bb = ((const bf16x8*)Wl)[col * 16 + (chunk ^ (col & 7))];
      acc[0][c] = __builtin_amdgcn_mfma_f32_16x16x32_bf16(a[0], bb, acc[0][c], 0, 0, 0);
      acc[1][c] = __builtin_amdgcn_mfma_f32_16x16x32_bf16(a[1], bb, acc[1][c], 0, 0, 0);
    }
  }
  #pragma unroll
  for (int rt = 0; rt < 2; ++rt) {
    #pragma unroll
    for (int c = 0; c < 8; ++c) {
      #pragma unroll
      for (int i = 0; i < 4; ++i) {
        int row = row0 + rt * 16 + (lane >> 4) * 4 + i;
        int col = c * 16 + (lane & 15);
        if (row < N) out[(size_t)row * 128 + col] = acc[rt][c][i];
      }
    }
  }
}

extern "C" void kernel_launch(void* const* d_in, const int* in_sizes, int n_in,
                              void* d_out, int out_size, void* d_ws, size_t ws_size,
                              hipStream_t stream) {
  const float* X     = (const float*)d_in[0];
  const float* X0    = (const float*)d_in[1];
  const float* degE  = (const float*)d_in[2];
  const float* degV  = (const float*)d_in[3];
  const float* W     = (const float*)d_in[4];
  const float* alpha = (const float*)d_in[5];
  const float* beta  = (const float*)d_in[6];
  const float* lnw   = (const float*)d_in[7];
  const float* lnb   = (const float*)d_in[8];
  const int* vertex  = (const int*)d_in[9];
  const int* edges   = (const int*)d_in[10];

  const int N = in_sizes[0] / D;
  const int E = in_sizes[2];
  const int M = in_sizes[9];

  const int BE = (E + 1023) >> 10;
  const int BV = (N + 1023) >> 10;

  char* p = (char*)d_ws;
  auto alloc = [&](size_t bytes) { char* r = p; p += (bytes + 255) & ~255ull; return r; };
  int* A_E  = (int*)alloc((size_t)E * 4);
  int* A_V  = (int*)alloc((size_t)N * 4);
  int* C_E  = (int*)alloc((size_t)E * 4);
  int* C_V  = (int*)alloc((size_t)N * 4);
  int* sums = (int*)alloc(1024);
  int* colE = (int*)alloc((size_t)M * 4);
  int* colV = (int*)alloc((size_t)M * 4);
  int* T_E  = (int*)alloc((size_t)NCH * E * 4);
  int* T_V  = (int*)alloc((size_t)NCH * N * 4);
  uint2* X_h  = (uint2*)alloc((size_t)N * D * 2);      // N x 128 fp16
  uint4* Xe4  = (uint4*)alloc((size_t)E * D * 2);      // E x 128 fp16
  ushort* Wbf = (ushort*)alloc(16384 * 2);
  uint4* Xi4  = (uint4*)X_h;  // X_h dead after edge_agg_q; alias for Xi (bf16)

  count_tab<<<NRR * NCH + CVT_BLOCKS, 512, 0, stream>>>(
      edges, vertex, T_E, T_V, E, N, M, X, X_h, N * D / 4);
  chunk_prefix<<<512, 256, 0, stream>>>(T_E, C_E, E, T_V, C_V, N);
  scan_local<<<BE + BV, 1024, 0, stream>>>(C_E, A_E, E, C_V, A_V, N, sums, BE);
  scan_sums<<<2, 1024, 0, stream>>>(sums, BE, BV);
  scan_add<<<BE + BV, 1024, 0, stream>>>(A_E, E, A_V, N, sums, BE);
  scatter_tab<<<NRR * NCH, 512, 0, stream>>>(edges, vertex, A_E, A_V, T_E, T_V,
                                             colE, colV, E, N, M);
  edge_agg_q<<<(E + 15) / 16, 256, 0, stream>>>((const uint4*)X_h, degE, A_E, C_E,
                                                colE, Xe4, E);
  vertex_ln_q<<<(N + 15) / 16, 256, 0, stream>>>(Xe4, X0, degV, lnw, lnb, alpha,
                                                 A_V, C_V, colV, Xi4, N);
  wprep_kernel<<<64, 256, 0, stream>>>(W, beta, Wbf);
  gemm_out<<<(N + 127) / 128, 256, 0, stream>>>((const ushort*)Xi4, Wbf, (float*)d_out, N);
}